// Round 4
// baseline (94.442 us; speedup 1.0000x reference)
//
#include <hip/hip_runtime.h>

typedef __bf16 bf16_t;
typedef __bf16 bf16x8 __attribute__((ext_vector_type(8)));
typedef __bf16 bf16x4 __attribute__((ext_vector_type(4)));
typedef float  f32x4  __attribute__((ext_vector_type(4)));
typedef _Float16 f16_t;
typedef _Float16 f16x8 __attribute__((ext_vector_type(8)));

#define TSEQ 4096
#define SEGS 8

// ---------------------------------------------------------------------------
// wsplit: W[1024][64] (q,k,v fp32) -> wT[192][1024] bf16 (transposed).
// Wq is pre-scaled by 0.125*log2(e) so attention scores land in exp2 domain.
// ---------------------------------------------------------------------------
__global__ __launch_bounds__(256) void wsplit_k(
    const float* __restrict__ Wq, const float* __restrict__ Wk,
    const float* __restrict__ Wv, bf16_t* __restrict__ wT)
{
    __shared__ bf16_t th[64][72];
    const int mat = blockIdx.x >> 4;
    const int kb  = (blockIdx.x & 15) * 64;
    const float* W = (mat == 0) ? Wq : ((mat == 1) ? Wk : Wv);
    const float scale = (mat == 0) ? 0.18033688011112042f : 1.0f;  // 0.125*log2e
    const int t  = threadIdx.x;
    const int kl = t >> 2;
    const int dc = (t & 3) * 16;
    #pragma unroll
    for (int i = 0; i < 4; ++i) {
        float4 v = *reinterpret_cast<const float4*>(W + (long)(kb + kl) * 64 + dc + 4 * i);
        th[dc + 4*i + 0][kl] = (bf16_t)(v.x * scale);
        th[dc + 4*i + 1][kl] = (bf16_t)(v.y * scale);
        th[dc + 4*i + 2][kl] = (bf16_t)(v.z * scale);
        th[dc + 4*i + 3][kl] = (bf16_t)(v.w * scale);
    }
    __syncthreads();
    const int d  = t >> 2;
    const int kc = (t & 3) * 16;
    bf16x8 a0 = *reinterpret_cast<const bf16x8*>(&th[d][kc]);
    bf16x8 a1 = *reinterpret_cast<const bf16x8*>(&th[d][kc + 8]);
    long o = (long)(mat * 64 + d) * 1024 + kb + kc;
    *reinterpret_cast<bf16x8*>(wT + o)     = a0;
    *reinterpret_cast<bf16x8*>(wT + o + 8) = a1;
}

// ---------------------------------------------------------------------------
// proj: [8192][192] = X @ W^T.  256 blocks x 32 rows, 8 waves (2M x 4N);
// wave = 16 rows x 3 N-tiles.  NO LDS, NO barriers in K-loop: W frags direct
// from global (L2-resident) with 2-deep register prefetch; X direct, 1-pass.
// Outputs: qh (exp2-domain scaled via Wq), kh, vt (transposed [64][8192]).
// ---------------------------------------------------------------------------
__global__ __launch_bounds__(512) void proj_mfma(
    const float* __restrict__ X, const bf16_t* __restrict__ wT,
    bf16_t* __restrict__ qh, bf16_t* __restrict__ kh, bf16_t* __restrict__ vt)
{
    __shared__ float vtl[64][34];

    const int tid  = threadIdx.x;
    const int lane = tid & 63;
    const int w    = tid >> 6;          // 0..7
    const int nw   = w & 3;             // N-split: nt = 3*nw + j
    const int mw   = w >> 2;            // M-split: 16-row tile
    const int q4 = lane & 15, g = lane >> 4;
    const long R0 = (long)blockIdx.x * 32;

    const float* xrow = X + (R0 + 16 * mw + q4) * 1024 + 8 * g;
    const bf16_t* wrow0 = wT + (long)((3 * nw + 0) * 16 + q4) * 1024 + 8 * g;
    const bf16_t* wrow1 = wT + (long)((3 * nw + 1) * 16 + q4) * 1024 + 8 * g;
    const bf16_t* wrow2 = wT + (long)((3 * nw + 2) * 16 + q4) * 1024 + 8 * g;

    f32x4 acc[3] = {};
    float4 xb[32][2];
    bf16x8 wb[32][3];

    #pragma unroll
    for (int i = 0; i < 2; ++i) {
        xb[i][0] = *reinterpret_cast<const float4*>(xrow + 32 * i);
        xb[i][1] = *reinterpret_cast<const float4*>(xrow + 32 * i + 4);
        wb[i][0] = *reinterpret_cast<const bf16x8*>(wrow0 + 32 * i);
        wb[i][1] = *reinterpret_cast<const bf16x8*>(wrow1 + 32 * i);
        wb[i][2] = *reinterpret_cast<const bf16x8*>(wrow2 + 32 * i);
    }

    #pragma unroll
    for (int ks = 0; ks < 32; ++ks) {
        if (ks + 2 < 32) {   // compile-time resolved (full unroll): 2-deep prefetch
            xb[ks+2][0] = *reinterpret_cast<const float4*>(xrow + 32 * (ks+2));
            xb[ks+2][1] = *reinterpret_cast<const float4*>(xrow + 32 * (ks+2) + 4);
            wb[ks+2][0] = *reinterpret_cast<const bf16x8*>(wrow0 + 32 * (ks+2));
            wb[ks+2][1] = *reinterpret_cast<const bf16x8*>(wrow1 + 32 * (ks+2));
            wb[ks+2][2] = *reinterpret_cast<const bf16x8*>(wrow2 + 32 * (ks+2));
        }
        const float4 x0 = xb[ks][0], x1 = xb[ks][1];
        bf16x8 af = {(bf16_t)x0.x, (bf16_t)x0.y, (bf16_t)x0.z, (bf16_t)x0.w,
                     (bf16_t)x1.x, (bf16_t)x1.y, (bf16_t)x1.z, (bf16_t)x1.w};
        acc[0] = __builtin_amdgcn_mfma_f32_16x16x32_bf16(af, wb[ks][0], acc[0], 0, 0, 0);
        acc[1] = __builtin_amdgcn_mfma_f32_16x16x32_bf16(af, wb[ks][1], acc[1], 0, 0, 0);
        acc[2] = __builtin_amdgcn_mfma_f32_16x16x32_bf16(af, wb[ks][2], acc[2], 0, 0, 0);
    }

    // epilogue: nt<4 -> q, nt<8 -> k, else v staged for transpose
    #pragma unroll
    for (int j = 0; j < 3; ++j) {
        const int nt = 3 * nw + j;
        #pragma unroll
        for (int r = 0; r < 4; ++r) {
            const long row = R0 + 16 * mw + 4 * g + r;
            const float vv = acc[j][r];
            if (nt < 4)      qh[row * 64 + nt * 16 + q4] = (bf16_t)vv;
            else if (nt < 8) kh[row * 64 + (nt - 4) * 16 + q4] = (bf16_t)vv;
            else             vtl[(nt - 8) * 16 + q4][16 * mw + 4 * g + r] = vv;
        }
    }
    __syncthreads();
    {
        const int d = tid >> 3, c = tid & 7;
        bf16x4 o;
        #pragma unroll
        for (int i = 0; i < 4; ++i) o[i] = (bf16_t)vtl[d][4 * c + i];
        *reinterpret_cast<bf16x4*>(vt + (long)d * 8192 + R0 + 4 * c) = o;
    }
}

// ---------------------------------------------------------------------------
// attn: flash, block = 64 queries (4 waves Msplit), round-robin causal
// segment split.  Software-pipelined: V(current) + K(next) loads issued
// before softmax so L2 latency hides under VALU work.  exp2 domain.
// ---------------------------------------------------------------------------
__global__ __launch_bounds__(256) void attn_mfma(
    const bf16_t* __restrict__ qh, const bf16_t* __restrict__ kh,
    const bf16_t* __restrict__ vt,
    f16_t* __restrict__ pO, float* __restrict__ pm, float* __restrict__ pl)
{
    __shared__ __align__(16) bf16_t P[4][8][16][8];
    __shared__ float ot[4][16][68];

    const int tid = threadIdx.x, lane = tid & 63, w = tid >> 6;
    const int q4 = lane & 15, g = lane >> 4;
    const int bx = blockIdx.x, b = blockIdx.y;
    const int tile = 63 - (bx >> 3);     // deep tiles first
    const int seg  = bx & 7;
    const int C = tile + 1;
    if (seg >= C) return;
    const long base = (long)b * TSEQ;
    const int r0 = tile * 64 + 16 * w;

    const bf16_t* qr = qh + (base + r0 + q4) * 64 + 8 * g;
    const bf16x8 qf0 = *reinterpret_cast<const bf16x8*>(qr);
    const bf16x8 qf1 = *reinterpret_cast<const bf16x8*>(qr + 32);

    auto loadK = [&](bf16x8 (&kf)[4][2], int kb) {
        #pragma unroll
        for (int kt = 0; kt < 4; ++kt) {
            const bf16_t* kr = kh + (base + kb + kt * 16 + q4) * 64 + 8 * g;
            kf[kt][0] = *reinterpret_cast<const bf16x8*>(kr);
            kf[kt][1] = *reinterpret_cast<const bf16x8*>(kr + 32);
        }
    };
    auto qkt = [&](const bf16x8 (&kf)[4][2], f32x4 (&sacc)[4]) {
        #pragma unroll
        for (int kt = 0; kt < 4; ++kt) {
            f32x4 a = {};
            a = __builtin_amdgcn_mfma_f32_16x16x32_bf16(kf[kt][0], qf0, a, 0, 0, 0);
            a = __builtin_amdgcn_mfma_f32_16x16x32_bf16(kf[kt][1], qf1, a, 0, 0, 0);
            sacc[kt] = a;
        }
    };

    float m = -1e30f, l = 0.f;
    f32x4 oacc[4] = {};
    bf16x8 kfA[4][2], kfB[4][2], vf[4][2];

    loadK(kfA, seg << 6);
    bool useA = true;

    for (int c = seg; c < C; c += SEGS) {
        const int kb = c << 6;
        // issue V loads for current chunk (consumed after softmax)
        #pragma unroll
        for (int dt = 0; dt < 4; ++dt) {
            const bf16_t* vr = vt + (long)(dt * 16 + q4) * 8192 + base + kb + 8 * g;
            vf[dt][0] = *reinterpret_cast<const bf16x8*>(vr);
            vf[dt][1] = *reinterpret_cast<const bf16x8*>(vr + 32);
        }
        // issue K prefetch for next chunk, then QK^T on current K set
        f32x4 sacc[4];
        if (useA) {
            if (c + SEGS < C) loadK(kfB, (c + SEGS) << 6);
            qkt(kfA, sacc);
        } else {
            if (c + SEGS < C) loadK(kfA, (c + SEGS) << 6);
            qkt(kfB, sacc);
        }
        useA = !useA;

        // online softmax in exp2 domain (lane: 16 scores of query q4)
        float p[16];
        const bool diag = (c == C - 1);
        float mx = -1e30f;
        #pragma unroll
        for (int kt = 0; kt < 4; ++kt)
            #pragma unroll
            for (int r = 0; r < 4; ++r) {
                float sv = sacc[kt][r];
                if (diag && (kb + kt * 16 + 4 * g + r > r0 + q4)) sv = -1e30f;
                p[kt * 4 + r] = sv;
                mx = fmaxf(mx, sv);
            }
        mx = fmaxf(mx, __shfl_xor(mx, 16));
        mx = fmaxf(mx, __shfl_xor(mx, 32));
        const float mnew = fmaxf(m, mx);
        const float alpha = __builtin_exp2f(m - mnew);
        m = mnew;
        float lsum = 0.f;
        #pragma unroll
        for (int i = 0; i < 16; ++i) { p[i] = __builtin_exp2f(p[i] - mnew); lsum += p[i]; }
        lsum += __shfl_xor(lsum, 16);
        lsum += __shfl_xor(lsum, 32);
        l = l * alpha + lsum;
        #pragma unroll
        for (int dt = 0; dt < 4; ++dt) oacc[dt] *= alpha;

        // pack P (bf16) into this wave's LDS tile
        #pragma unroll
        for (int kt = 0; kt < 4; ++kt) {
            const int cb = 2 * kt + (g >> 1);
            const int ki = (g & 1) << 2;
            bf16x4 hv = {(bf16_t)p[4*kt+0], (bf16_t)p[4*kt+1],
                         (bf16_t)p[4*kt+2], (bf16_t)p[4*kt+3]};
            *reinterpret_cast<bf16x4*>(&P[w][cb][q4][ki]) = hv;
        }
        // PV: O^T += V^T x P^T  (V already in flight, covered by softmax)
        bf16x8 ph0 = *reinterpret_cast<const bf16x8*>(&P[w][g][q4][0]);
        bf16x8 ph1 = *reinterpret_cast<const bf16x8*>(&P[w][4 + g][q4][0]);
        #pragma unroll
        for (int dt = 0; dt < 4; ++dt) {
            oacc[dt] = __builtin_amdgcn_mfma_f32_16x16x32_bf16(vf[dt][0], ph0, oacc[dt], 0, 0, 0);
            oacc[dt] = __builtin_amdgcn_mfma_f32_16x16x32_bf16(vf[dt][1], ph1, oacc[dt], 0, 0, 0);
        }
    }

    // epilogue: normalize, transpose via LDS, store f16 partial
    const float invl = 1.0f / l;
    #pragma unroll
    for (int dt = 0; dt < 4; ++dt)
        #pragma unroll
        for (int r = 0; r < 4; ++r)
            ot[w][q4][dt * 16 + 4 * g + r] = oacc[dt][r] * invl;

    const long pbase = (((long)b * 64 + tile) * SEGS + seg) * 64;
    {
        const int q  = lane >> 2;
        const int dc = (lane & 3) * 16;
        f16x8 o0, o1;
        #pragma unroll
        for (int i = 0; i < 8; ++i) {
            o0[i] = (f16_t)ot[w][q][dc + i];
            o1[i] = (f16_t)ot[w][q][dc + 8 + i];
        }
        f16_t* dst = pO + (pbase + 16 * w + q) * 64 + dc;
        *reinterpret_cast<f16x8*>(dst)     = o0;
        *reinterpret_cast<f16x8*>(dst + 8) = o1;
    }
    if (g == 0) {
        pm[pbase + 16 * w + q4] = m;
        pl[pbase + 16 * w + q4] = l;
    }
}

// ---------------------------------------------------------------------------
// merge: combine active segs per 64q tile -> final O (fp32).  exp2 domain.
// ---------------------------------------------------------------------------
__global__ __launch_bounds__(256) void merge_k(
    const f16_t* __restrict__ pO, const float* __restrict__ pm,
    const float* __restrict__ pl, float* __restrict__ O)
{
    const int tile = blockIdx.x, b = blockIdx.y;
    const int C = tile + 1;
    const int S = (C < SEGS) ? C : SEGS;
    const int t = threadIdx.x;
    const int q = t >> 2, dc = (t & 3) * 16;
    const long pb = ((long)b * 64 + tile) * SEGS;

    float mstar = -1e30f;
    for (int s = 0; s < S; ++s) mstar = fmaxf(mstar, pm[(pb + s) * 64 + q]);
    float L = 0.f;
    float o[16];
    #pragma unroll
    for (int i = 0; i < 16; ++i) o[i] = 0.f;
    for (int s = 0; s < S; ++s) {
        const float ws = __builtin_exp2f(pm[(pb + s) * 64 + q] - mstar) * pl[(pb + s) * 64 + q];
        L += ws;
        const f16_t* src = pO + ((pb + s) * 64 + q) * 64 + dc;
        f16x8 a0 = *reinterpret_cast<const f16x8*>(src);
        f16x8 a1 = *reinterpret_cast<const f16x8*>(src + 8);
        #pragma unroll
        for (int i = 0; i < 8; ++i) {
            o[i]     += ws * (float)a0[i];
            o[8 + i] += ws * (float)a1[i];
        }
    }
    const float inv = 1.0f / L;
    float* dst = O + ((long)b * TSEQ + tile * 64 + q) * 64 + dc;
    #pragma unroll
    for (int i = 0; i < 4; ++i) {
        f32x4 v = {o[4*i] * inv, o[4*i+1] * inv, o[4*i+2] * inv, o[4*i+3] * inv};
        *reinterpret_cast<f32x4*>(dst + 4 * i) = v;
    }
}

extern "C" void kernel_launch(void* const* d_in, const int* in_sizes, int n_in,
                              void* d_out, int out_size, void* d_ws, size_t ws_size,
                              hipStream_t stream)
{
    const float* X  = (const float*)d_in[0];
    const float* Wq = (const float*)d_in[1];
    const float* Wk = (const float*)d_in[2];
    const float* Wv = (const float*)d_in[3];
    float* O = (float*)d_out;

    char* ws = (char*)d_ws;
    size_t off = 0;
    bf16_t* wT = (bf16_t*)(ws + off); off += 192 * 1024 * sizeof(bf16_t);
    bf16_t* qh = (bf16_t*)(ws + off); off += 8192L * 64 * sizeof(bf16_t);
    bf16_t* kh = (bf16_t*)(ws + off); off += 8192L * 64 * sizeof(bf16_t);
    bf16_t* vt = (bf16_t*)(ws + off); off += 64L * 8192 * sizeof(bf16_t);
    f16_t*  pO = (f16_t*)(ws + off);  off += 2L * 64 * SEGS * 64 * 64 * sizeof(f16_t);
    float*  pm = (float*)(ws + off);  off += 2L * 64 * SEGS * 64 * sizeof(float);
    float*  pl = (float*)(ws + off);  off += 2L * 64 * SEGS * 64 * sizeof(float);

    wsplit_k <<<48, 256, 0, stream>>>(Wq, Wk, Wv, wT);
    proj_mfma<<<256, 512, 0, stream>>>(X, wT, qh, kh, vt);
    attn_mfma<<<dim3(512, 2), 256, 0, stream>>>(qh, kh, vt, pO, pm, pl);
    merge_k  <<<dim3(64, 2), 256, 0, stream>>>(pO, pm, pl, O);
}

// Round 5
// 53.761 us; speedup vs baseline: 1.7567x; 1.7567x over previous
//
#include <hip/hip_runtime.h>

typedef __bf16 bf16_t;
typedef __bf16 bf16x8 __attribute__((ext_vector_type(8)));
typedef __bf16 bf16x4 __attribute__((ext_vector_type(4)));
typedef float  f32x4  __attribute__((ext_vector_type(4)));
typedef _Float16 f16_t;
typedef _Float16 f16x8 __attribute__((ext_vector_type(8)));

#define TSEQ 4096
#define SEGS 8

// ---------------------------------------------------------------------------
// wsplit: W[1024][64] (q,k,v fp32) -> wT[192][1024] bf16 (transposed).
// Wq pre-scaled by 0.125*log2(e) so attention scores land in exp2 domain.
// ---------------------------------------------------------------------------
__global__ __launch_bounds__(256) void wsplit_k(
    const float* __restrict__ Wq, const float* __restrict__ Wk,
    const float* __restrict__ Wv, bf16_t* __restrict__ wT)
{
    __shared__ bf16_t th[64][72];
    const int mat = blockIdx.x >> 4;
    const int kb  = (blockIdx.x & 15) * 64;
    const float* W = (mat == 0) ? Wq : ((mat == 1) ? Wk : Wv);
    const float scale = (mat == 0) ? 0.18033688011112042f : 1.0f;
    const int t  = threadIdx.x;
    const int kl = t >> 2;
    const int dc = (t & 3) * 16;
    #pragma unroll
    for (int i = 0; i < 4; ++i) {
        float4 v = *reinterpret_cast<const float4*>(W + (long)(kb + kl) * 64 + dc + 4 * i);
        th[dc + 4*i + 0][kl] = (bf16_t)(v.x * scale);
        th[dc + 4*i + 1][kl] = (bf16_t)(v.y * scale);
        th[dc + 4*i + 2][kl] = (bf16_t)(v.z * scale);
        th[dc + 4*i + 3][kl] = (bf16_t)(v.w * scale);
    }
    __syncthreads();
    const int d  = t >> 2;
    const int kc = (t & 3) * 16;
    bf16x8 a0 = *reinterpret_cast<const bf16x8*>(&th[d][kc]);
    bf16x8 a1 = *reinterpret_cast<const bf16x8*>(&th[d][kc + 8]);
    long o = (long)(mat * 64 + d) * 1024 + kb + kc;
    *reinterpret_cast<bf16x8*>(wT + o)     = a0;
    *reinterpret_cast<bf16x8*>(wT + o + 8) = a1;
}

// ---------------------------------------------------------------------------
// proj: [8192][192] = X @ W^T.  512 blocks = (128 row-groups of 64) x (4 N-
// blocks of 48 cols); 4 waves M-split (16 rows each).  X loaded direct to
// frags per wave (2-step ping-pong, named sets).  W slice dbuf in LDS
// (pad-72), staged T14 (issue-early regs -> write-late), 1 barrier/step.
// nb-major block mapping so same-rg blocks share an XCD's L2 for X.
// ---------------------------------------------------------------------------
__global__ __launch_bounds__(256) void proj_mfma(
    const float* __restrict__ X, const bf16_t* __restrict__ wT,
    bf16_t* __restrict__ qh, bf16_t* __restrict__ kh, bf16_t* __restrict__ vt)
{
    __shared__ __align__(16) unsigned char smem[13824];
    bf16_t (*wl)[48][72] = reinterpret_cast<bf16_t(*)[48][72]>(smem);   // [2][48][72]
    float  (*vtl)[68]    = reinterpret_cast<float(*)[68]>(smem);        // [48][68] (union)

    const int tid = threadIdx.x, lane = tid & 63;
    const int mw  = tid >> 6;               // wave = M-split (16 rows)
    const int q4 = lane & 15, g = lane >> 4;
    const int bx = blockIdx.x;
    const int rg = bx & 127, nb = bx >> 7;  // nb-major: same-rg -> same XCD
    const long R0 = (long)rg * 64;

    const float* xrow = X + (R0 + 16 * mw + q4) * 1024 + 8 * g;

    // W staging: threads 0..191: row t>>2 (0..47), cols (t&3)*16..+15
    const int wrow = tid >> 2, c16 = (tid & 3) * 16;
    const bf16_t* wsrc = wT + (long)(48 * nb + wrow) * 1024 + c16;
    const bool wact = (tid < 192);

    bf16x8 wr0, wr1;
    float4 xE[4], xO[4];
    f32x4 acc[3] = {};

    auto loadW = [&](int t) {
        if (wact) {
            wr0 = *reinterpret_cast<const bf16x8*>(wsrc + t * 64);
            wr1 = *reinterpret_cast<const bf16x8*>(wsrc + t * 64 + 8);
        }
    };
    auto writeW = [&](int buf) {
        if (wact) {
            *reinterpret_cast<bf16x8*>(&wl[buf][wrow][c16])     = wr0;
            *reinterpret_cast<bf16x8*>(&wl[buf][wrow][c16 + 8]) = wr1;
        }
    };
    auto loadX = [&](int t, float4 (&xc)[4]) {
        xc[0] = *reinterpret_cast<const float4*>(xrow + t * 64);
        xc[1] = *reinterpret_cast<const float4*>(xrow + t * 64 + 4);
        xc[2] = *reinterpret_cast<const float4*>(xrow + t * 64 + 32);
        xc[3] = *reinterpret_cast<const float4*>(xrow + t * 64 + 36);
    };

    loadW(0); writeW(0);
    loadW(1);
    loadX(0, xE); loadX(1, xO);
    __syncthreads();

    auto stepf = [&](int t, float4 (&xc)[4]) {
        if (t + 1 < 16) {                    // stage W(t+1), issue W(t+2)
            writeW((t + 1) & 1);
            loadW(t + 2 < 16 ? t + 2 : 15);
        }
        bf16x8 a0 = {(bf16_t)xc[0].x, (bf16_t)xc[0].y, (bf16_t)xc[0].z, (bf16_t)xc[0].w,
                     (bf16_t)xc[1].x, (bf16_t)xc[1].y, (bf16_t)xc[1].z, (bf16_t)xc[1].w};
        bf16x8 a1 = {(bf16_t)xc[2].x, (bf16_t)xc[2].y, (bf16_t)xc[2].z, (bf16_t)xc[2].w,
                     (bf16_t)xc[3].x, (bf16_t)xc[3].y, (bf16_t)xc[3].z, (bf16_t)xc[3].w};
        if (t + 2 < 16) loadX(t + 2, xc);    // 2-step-ahead X reissue
        #pragma unroll
        for (int j = 0; j < 3; ++j) {
            bf16x8 b0 = *reinterpret_cast<const bf16x8*>(&wl[t & 1][16 * j + q4][8 * g]);
            bf16x8 b1 = *reinterpret_cast<const bf16x8*>(&wl[t & 1][16 * j + q4][8 * g + 32]);
            acc[j] = __builtin_amdgcn_mfma_f32_16x16x32_bf16(a0, b0, acc[j], 0, 0, 0);
            acc[j] = __builtin_amdgcn_mfma_f32_16x16x32_bf16(a1, b1, acc[j], 0, 0, 0);
        }
        __syncthreads();
    };
    #pragma unroll
    for (int tt = 0; tt < 16; tt += 2) { stepf(tt, xE); stepf(tt + 1, xO); }

    // epilogue: nt<4 -> q, nt<8 -> k, else v staged in vtl for transpose
    const int vbase = (nb == 2) ? 0 : 16;
    #pragma unroll
    for (int j = 0; j < 3; ++j) {
        const int nt = 3 * nb + j;
        #pragma unroll
        for (int r = 0; r < 4; ++r) {
            const long row = R0 + 16 * mw + 4 * g + r;
            const float vv = acc[j][r];
            if (nt < 4)      qh[row * 64 + nt * 16 + q4] = (bf16_t)vv;
            else if (nt < 8) kh[row * 64 + (nt - 4) * 16 + q4] = (bf16_t)vv;
            else             vtl[(nt - 8) * 16 + q4 - vbase][16 * mw + 4 * g + r] = vv;
        }
    }
    if (nb >= 2) {
        __syncthreads();
        const int nd = (nb == 2) ? 16 : 48;
        const int dl = tid >> 2, cc = (tid & 3) * 16;
        if (dl < nd) {
            bf16x8 o0, o1;
            #pragma unroll
            for (int i = 0; i < 8; ++i) {
                o0[i] = (bf16_t)vtl[dl][cc + i];
                o1[i] = (bf16_t)vtl[dl][cc + 8 + i];
            }
            bf16_t* dst = vt + (long)(vbase + dl) * 8192 + R0 + cc;
            *reinterpret_cast<bf16x8*>(dst)     = o0;
            *reinterpret_cast<bf16x8*>(dst + 8) = o1;
        }
    }
}

// ---------------------------------------------------------------------------
// attn: flash, block = 64 queries (4 waves M-split), seg round-robin causal
// split.  K and V double-buffered in LDS (pad-72), staged T14: loads issued
// one full chunk early (reg-held), written after the barrier.  exp2 domain.
// ---------------------------------------------------------------------------
__global__ __launch_bounds__(256) void attn_mfma(
    const bf16_t* __restrict__ qh, const bf16_t* __restrict__ kh,
    const bf16_t* __restrict__ vt,
    f16_t* __restrict__ pO, float* __restrict__ pm, float* __restrict__ pl)
{
    __shared__ __align__(16) unsigned char smem[54272];
    bf16_t (*kl)[64][72]  = reinterpret_cast<bf16_t(*)[64][72]>(smem);        // [2]
    bf16_t (*vl)[64][72]  = reinterpret_cast<bf16_t(*)[64][72]>(smem + 18432);// [2]
    bf16_t (*P)[8][16][8] = reinterpret_cast<bf16_t(*)[8][16][8]>(smem + 36864); // [4]
    float  (*ot)[16][68]  = reinterpret_cast<float(*)[16][68]>(smem + 36864);    // [4] union w/ P

    const int tid = threadIdx.x, lane = tid & 63, w = tid >> 6;
    const int q4 = lane & 15, g = lane >> 4;
    const int bx = blockIdx.x, b = blockIdx.y;
    const int tile = 63 - (bx >> 3);     // heavy tiles first
    const int seg  = bx & 7;
    const int C = tile + 1;
    if (seg >= C) return;
    const long base = (long)b * TSEQ;
    const int r0 = tile * 64 + 16 * w;

    const bf16_t* qr = qh + (base + r0 + q4) * 64 + 8 * g;
    const bf16x8 qf0 = *reinterpret_cast<const bf16x8*>(qr);
    const bf16x8 qf1 = *reinterpret_cast<const bf16x8*>(qr + 32);

    // staging map: thread t: row t>>2 (0..63), cols (t&3)*16..+15
    const int srow = tid >> 2, sc = (tid & 3) * 16;
    const bf16_t* ksrc = kh + (base + srow) * 64 + sc;
    const bf16_t* vsrc = vt + (long)srow * 8192 + base + sc;
    bf16x8 kr0, kr1, vr0, vr1;
    auto loadKV = [&](int kb) {
        kr0 = *reinterpret_cast<const bf16x8*>(ksrc + (long)kb * 64);
        kr1 = *reinterpret_cast<const bf16x8*>(ksrc + (long)kb * 64 + 8);
        vr0 = *reinterpret_cast<const bf16x8*>(vsrc + kb);
        vr1 = *reinterpret_cast<const bf16x8*>(vsrc + kb + 8);
    };
    auto writeKV = [&](int buf) {
        *reinterpret_cast<bf16x8*>(&kl[buf][srow][sc])     = kr0;
        *reinterpret_cast<bf16x8*>(&kl[buf][srow][sc + 8]) = kr1;
        *reinterpret_cast<bf16x8*>(&vl[buf][srow][sc])     = vr0;
        *reinterpret_cast<bf16x8*>(&vl[buf][srow][sc + 8]) = vr1;
    };

    float m = -1e30f, l = 0.f;
    f32x4 oacc[4] = {};

    loadKV(seg << 6);
    writeKV(0);
    { int c1 = seg + SEGS; loadKV((c1 < C ? c1 : seg) << 6); }
    __syncthreads();

    int i = 0;
    for (int c = seg; c < C; c += SEGS, ++i) {
        const int buf = i & 1;
        if (c + SEGS < C) {                   // stage next chunk, issue next+1
            writeKV(buf ^ 1);
            int cn = c + 2 * SEGS;
            loadKV((cn < C ? cn : c + SEGS) << 6);
        }
        const int kb = c << 6;

        // ---- QK^T (swapped): S^T rows = keys, cols = queries
        f32x4 sacc[4];
        #pragma unroll
        for (int kt = 0; kt < 4; ++kt) {
            bf16x8 kf0 = *reinterpret_cast<const bf16x8*>(&kl[buf][kt * 16 + q4][8 * g]);
            bf16x8 kf1 = *reinterpret_cast<const bf16x8*>(&kl[buf][kt * 16 + q4][8 * g + 32]);
            f32x4 a = {};
            a = __builtin_amdgcn_mfma_f32_16x16x32_bf16(kf0, qf0, a, 0, 0, 0);
            a = __builtin_amdgcn_mfma_f32_16x16x32_bf16(kf1, qf1, a, 0, 0, 0);
            sacc[kt] = a;
        }

        // ---- online softmax (exp2 domain; lane: 16 scores of query q4)
        float p[16];
        const bool diag = (c == C - 1);
        float mx = -1e30f;
        #pragma unroll
        for (int kt = 0; kt < 4; ++kt)
            #pragma unroll
            for (int r = 0; r < 4; ++r) {
                float sv = sacc[kt][r];
                if (diag && (kb + kt * 16 + 4 * g + r > r0 + q4)) sv = -1e30f;
                p[kt * 4 + r] = sv;
                mx = fmaxf(mx, sv);
            }
        mx = fmaxf(mx, __shfl_xor(mx, 16));
        mx = fmaxf(mx, __shfl_xor(mx, 32));
        const float mnew = fmaxf(m, mx);
        const float alpha = __builtin_exp2f(m - mnew);
        m = mnew;
        float lsum = 0.f;
        #pragma unroll
        for (int ii = 0; ii < 16; ++ii) { p[ii] = __builtin_exp2f(p[ii] - mnew); lsum += p[ii]; }
        lsum += __shfl_xor(lsum, 16);
        lsum += __shfl_xor(lsum, 32);
        l = l * alpha + lsum;
        #pragma unroll
        for (int dt = 0; dt < 4; ++dt) oacc[dt] *= alpha;

        // ---- pack P (bf16) into this wave's LDS tile
        #pragma unroll
        for (int kt = 0; kt < 4; ++kt) {
            const int cb = 2 * kt + (g >> 1);
            const int ki = (g & 1) << 2;
            bf16x4 hv = {(bf16_t)p[4*kt+0], (bf16_t)p[4*kt+1],
                         (bf16_t)p[4*kt+2], (bf16_t)p[4*kt+3]};
            *reinterpret_cast<bf16x4*>(&P[w][cb][q4][ki]) = hv;
        }
        // ---- PV: O^T += V^T x P^T
        bf16x8 ph0 = *reinterpret_cast<const bf16x8*>(&P[w][g][q4][0]);
        bf16x8 ph1 = *reinterpret_cast<const bf16x8*>(&P[w][4 + g][q4][0]);
        #pragma unroll
        for (int dt = 0; dt < 4; ++dt) {
            bf16x8 va0 = *reinterpret_cast<const bf16x8*>(&vl[buf][dt * 16 + q4][8 * g]);
            bf16x8 va1 = *reinterpret_cast<const bf16x8*>(&vl[buf][dt * 16 + q4][8 * g + 32]);
            oacc[dt] = __builtin_amdgcn_mfma_f32_16x16x32_bf16(va0, ph0, oacc[dt], 0, 0, 0);
            oacc[dt] = __builtin_amdgcn_mfma_f32_16x16x32_bf16(va1, ph1, oacc[dt], 0, 0, 0);
        }
        __syncthreads();
    }

    // ---- epilogue: normalize, transpose via LDS (ot unions P; P is dead
    // after the final in-loop barrier), store f16 partial
    const float invl = 1.0f / l;
    #pragma unroll
    for (int dt = 0; dt < 4; ++dt)
        #pragma unroll
        for (int r = 0; r < 4; ++r)
            ot[w][q4][dt * 16 + 4 * g + r] = oacc[dt][r] * invl;

    const long pbase = (((long)b * 64 + tile) * SEGS + seg) * 64;
    {
        const int q  = lane >> 2;
        const int dc = (lane & 3) * 16;
        f16x8 o0, o1;
        #pragma unroll
        for (int ii = 0; ii < 8; ++ii) {
            o0[ii] = (f16_t)ot[w][q][dc + ii];
            o1[ii] = (f16_t)ot[w][q][dc + 8 + ii];
        }
        f16_t* dst = pO + (pbase + 16 * w + q) * 64 + dc;
        *reinterpret_cast<f16x8*>(dst)     = o0;
        *reinterpret_cast<f16x8*>(dst + 8) = o1;
    }
    if (g == 0) {
        pm[pbase + 16 * w + q4] = m;
        pl[pbase + 16 * w + q4] = l;
    }
}

// ---------------------------------------------------------------------------
// merge: combine active segs per 64q tile -> final O (fp32).  exp2 domain.
// ---------------------------------------------------------------------------
__global__ __launch_bounds__(256) void merge_k(
    const f16_t* __restrict__ pO, const float* __restrict__ pm,
    const float* __restrict__ pl, float* __restrict__ O)
{
    const int tile = blockIdx.x, b = blockIdx.y;
    const int C = tile + 1;
    const int S = (C < SEGS) ? C : SEGS;
    const int t = threadIdx.x;
    const int q = t >> 2, dc = (t & 3) * 16;
    const long pb = ((long)b * 64 + tile) * SEGS;

    float mstar = -1e30f;
    for (int s = 0; s < S; ++s) mstar = fmaxf(mstar, pm[(pb + s) * 64 + q]);
    float L = 0.f;
    float o[16];
    #pragma unroll
    for (int i = 0; i < 16; ++i) o[i] = 0.f;
    for (int s = 0; s < S; ++s) {
        const float ws = __builtin_exp2f(pm[(pb + s) * 64 + q] - mstar) * pl[(pb + s) * 64 + q];
        L += ws;
        const f16_t* src = pO + ((pb + s) * 64 + q) * 64 + dc;
        f16x8 a0 = *reinterpret_cast<const f16x8*>(src);
        f16x8 a1 = *reinterpret_cast<const f16x8*>(src + 8);
        #pragma unroll
        for (int i = 0; i < 8; ++i) {
            o[i]     += ws * (float)a0[i];
            o[8 + i] += ws * (float)a1[i];
        }
    }
    const float inv = 1.0f / L;
    float* dst = O + ((long)b * TSEQ + tile * 64 + q) * 64 + dc;
    #pragma unroll
    for (int i = 0; i < 4; ++i) {
        f32x4 v = {o[4*i] * inv, o[4*i+1] * inv, o[4*i+2] * inv, o[4*i+3] * inv};
        *reinterpret_cast<f32x4*>(dst + 4 * i) = v;
    }
}

extern "C" void kernel_launch(void* const* d_in, const int* in_sizes, int n_in,
                              void* d_out, int out_size, void* d_ws, size_t ws_size,
                              hipStream_t stream)
{
    const float* X  = (const float*)d_in[0];
    const float* Wq = (const float*)d_in[1];
    const float* Wk = (const float*)d_in[2];
    const float* Wv = (const float*)d_in[3];
    float* O = (float*)d_out;

    char* ws = (char*)d_ws;
    size_t off = 0;
    bf16_t* wT = (bf16_t*)(ws + off); off += 192 * 1024 * sizeof(bf16_t);
    bf16_t* qh = (bf16_t*)(ws + off); off += 8192L * 64 * sizeof(bf16_t);
    bf16_t* kh = (bf16_t*)(ws + off); off += 8192L * 64 * sizeof(bf16_t);
    bf16_t* vt = (bf16_t*)(ws + off); off += 64L * 8192 * sizeof(bf16_t);
    f16_t*  pO = (f16_t*)(ws + off);  off += 2L * 64 * SEGS * 64 * 64 * sizeof(f16_t);
    float*  pm = (float*)(ws + off);  off += 2L * 64 * SEGS * 64 * sizeof(float);
    float*  pl = (float*)(ws + off);  off += 2L * 64 * SEGS * 64 * sizeof(float);

    wsplit_k <<<48, 256, 0, stream>>>(Wq, Wk, Wv, wT);
    proj_mfma<<<512, 256, 0, stream>>>(X, wT, qh, kh, vt);
    attn_mfma<<<dim3(512, 2), 256, 0, stream>>>(qh, kh, vt, pO, pm, pl);
    merge_k  <<<dim3(64, 2), 256, 0, stream>>>(pO, pm, pl, O);
}

// Round 6
// 52.855 us; speedup vs baseline: 1.7868x; 1.0171x over previous
//
#include <hip/hip_runtime.h>

typedef __bf16 bf16_t;
typedef __bf16 bf16x8 __attribute__((ext_vector_type(8)));
typedef __bf16 bf16x4 __attribute__((ext_vector_type(4)));
typedef float  f32x4  __attribute__((ext_vector_type(4)));
typedef _Float16 f16_t;
typedef _Float16 f16x8 __attribute__((ext_vector_type(8)));

#define TSEQ 4096
#define SEGS 8

// Barrier that waits only LDS ops (lgkmcnt), NOT vmcnt: in-flight global
// prefetch loads survive the barrier (HIP __syncthreads drains vmcnt(0),
// which serializes the whole pipeline).  sched_barrier(0) fences hoisting.
__device__ __forceinline__ void barrier_lds() {
    __builtin_amdgcn_sched_barrier(0);
    asm volatile("s_waitcnt lgkmcnt(0)" ::: "memory");
    __builtin_amdgcn_s_barrier();
    __builtin_amdgcn_sched_barrier(0);
}

// ---------------------------------------------------------------------------
// wsplit: W[1024][64] (q,k,v fp32) -> wT[192][1024] bf16 (transposed).
// Wq pre-scaled by 0.125*log2(e) so attention scores land in exp2 domain.
// ---------------------------------------------------------------------------
__global__ __launch_bounds__(256) void wsplit_k(
    const float* __restrict__ Wq, const float* __restrict__ Wk,
    const float* __restrict__ Wv, bf16_t* __restrict__ wT)
{
    __shared__ bf16_t th[64][72];
    const int mat = blockIdx.x >> 4;
    const int kb  = (blockIdx.x & 15) * 64;
    const float* W = (mat == 0) ? Wq : ((mat == 1) ? Wk : Wv);
    const float scale = (mat == 0) ? 0.18033688011112042f : 1.0f;
    const int t  = threadIdx.x;
    const int kl = t >> 2;
    const int dc = (t & 3) * 16;
    #pragma unroll
    for (int i = 0; i < 4; ++i) {
        float4 v = *reinterpret_cast<const float4*>(W + (long)(kb + kl) * 64 + dc + 4 * i);
        th[dc + 4*i + 0][kl] = (bf16_t)(v.x * scale);
        th[dc + 4*i + 1][kl] = (bf16_t)(v.y * scale);
        th[dc + 4*i + 2][kl] = (bf16_t)(v.z * scale);
        th[dc + 4*i + 3][kl] = (bf16_t)(v.w * scale);
    }
    __syncthreads();
    const int d  = t >> 2;
    const int kc = (t & 3) * 16;
    bf16x8 a0 = *reinterpret_cast<const bf16x8*>(&th[d][kc]);
    bf16x8 a1 = *reinterpret_cast<const bf16x8*>(&th[d][kc + 8]);
    long o = (long)(mat * 64 + d) * 1024 + kb + kc;
    *reinterpret_cast<bf16x8*>(wT + o)     = a0;
    *reinterpret_cast<bf16x8*>(wT + o + 8) = a1;
}

// ---------------------------------------------------------------------------
// proj: [8192][192] = X @ W^T.  512 blocks = 128 row-groups x 4 N-blocks;
// 4 waves M-split.  X direct-to-frags (2-step ping-pong), W dbuf in LDS.
// In-loop barriers are lgkm-only so X/W prefetches stay in flight.
// ---------------------------------------------------------------------------
__global__ __launch_bounds__(256, 2) void proj_mfma(
    const float* __restrict__ X, const bf16_t* __restrict__ wT,
    bf16_t* __restrict__ qh, bf16_t* __restrict__ kh, bf16_t* __restrict__ vt)
{
    __shared__ __align__(16) unsigned char smem[13824];
    bf16_t (*wl)[48][72] = reinterpret_cast<bf16_t(*)[48][72]>(smem);   // [2][48][72]
    float  (*vtl)[68]    = reinterpret_cast<float(*)[68]>(smem);        // [48][68] (union)

    const int tid = threadIdx.x, lane = tid & 63;
    const int mw  = tid >> 6;
    const int q4 = lane & 15, g = lane >> 4;
    const int bx = blockIdx.x;
    const int rg = bx & 127, nb = bx >> 7;
    const long R0 = (long)rg * 64;

    const float* xrow = X + (R0 + 16 * mw + q4) * 1024 + 8 * g;

    const int wrow = tid >> 2, c16 = (tid & 3) * 16;
    const bf16_t* wsrc = wT + (long)(48 * nb + wrow) * 1024 + c16;
    const bool wact = (tid < 192);

    bf16x8 wr0, wr1;
    float4 xE[4], xO[4];
    f32x4 acc[3] = {};

    auto loadW = [&](int t) {
        if (wact) {
            wr0 = *reinterpret_cast<const bf16x8*>(wsrc + t * 64);
            wr1 = *reinterpret_cast<const bf16x8*>(wsrc + t * 64 + 8);
        }
    };
    auto writeW = [&](int buf) {
        if (wact) {
            *reinterpret_cast<bf16x8*>(&wl[buf][wrow][c16])     = wr0;
            *reinterpret_cast<bf16x8*>(&wl[buf][wrow][c16 + 8]) = wr1;
        }
    };
    auto loadX = [&](int t, float4 (&xc)[4]) {
        xc[0] = *reinterpret_cast<const float4*>(xrow + t * 64);
        xc[1] = *reinterpret_cast<const float4*>(xrow + t * 64 + 4);
        xc[2] = *reinterpret_cast<const float4*>(xrow + t * 64 + 32);
        xc[3] = *reinterpret_cast<const float4*>(xrow + t * 64 + 36);
    };

    loadW(0); writeW(0);
    loadW(1);
    loadX(0, xE); loadX(1, xO);
    asm volatile("" ::: "memory");      // pin prefetch issue
    barrier_lds();

    auto stepf = [&](int t, float4 (&xc)[4]) {
        if (t + 1 < 16) {                    // stage W(t+1), issue W(t+2)
            writeW((t + 1) & 1);
            loadW(t + 2 < 16 ? t + 2 : 15);
        }
        bf16x8 a0 = {(bf16_t)xc[0].x, (bf16_t)xc[0].y, (bf16_t)xc[0].z, (bf16_t)xc[0].w,
                     (bf16_t)xc[1].x, (bf16_t)xc[1].y, (bf16_t)xc[1].z, (bf16_t)xc[1].w};
        bf16x8 a1 = {(bf16_t)xc[2].x, (bf16_t)xc[2].y, (bf16_t)xc[2].z, (bf16_t)xc[2].w,
                     (bf16_t)xc[3].x, (bf16_t)xc[3].y, (bf16_t)xc[3].z, (bf16_t)xc[3].w};
        if (t + 2 < 16) loadX(t + 2, xc);    // 2-step-ahead X reissue
        asm volatile("" ::: "memory");       // pin prefetch issue
        __builtin_amdgcn_s_setprio(1);
        #pragma unroll
        for (int j = 0; j < 3; ++j) {
            bf16x8 b0 = *reinterpret_cast<const bf16x8*>(&wl[t & 1][16 * j + q4][8 * g]);
            bf16x8 b1 = *reinterpret_cast<const bf16x8*>(&wl[t & 1][16 * j + q4][8 * g + 32]);
            acc[j] = __builtin_amdgcn_mfma_f32_16x16x32_bf16(a0, b0, acc[j], 0, 0, 0);
            acc[j] = __builtin_amdgcn_mfma_f32_16x16x32_bf16(a1, b1, acc[j], 0, 0, 0);
        }
        __builtin_amdgcn_s_setprio(0);
        barrier_lds();
    };
    #pragma unroll
    for (int tt = 0; tt < 16; tt += 2) { stepf(tt, xE); stepf(tt + 1, xO); }

    // epilogue: nt<4 -> q, nt<8 -> k, else v staged in vtl for transpose
    const int vbase = (nb == 2) ? 0 : 16;
    #pragma unroll
    for (int j = 0; j < 3; ++j) {
        const int nt = 3 * nb + j;
        #pragma unroll
        for (int r = 0; r < 4; ++r) {
            const long row = R0 + 16 * mw + 4 * g + r;
            const float vv = acc[j][r];
            if (nt < 4)      qh[row * 64 + nt * 16 + q4] = (bf16_t)vv;
            else if (nt < 8) kh[row * 64 + (nt - 4) * 16 + q4] = (bf16_t)vv;
            else             vtl[(nt - 8) * 16 + q4 - vbase][16 * mw + 4 * g + r] = vv;
        }
    }
    if (nb >= 2) {
        barrier_lds();
        const int nd = (nb == 2) ? 16 : 48;
        const int dl = tid >> 2, cc = (tid & 3) * 16;
        if (dl < nd) {
            bf16x8 o0, o1;
            #pragma unroll
            for (int i = 0; i < 8; ++i) {
                o0[i] = (bf16_t)vtl[dl][cc + i];
                o1[i] = (bf16_t)vtl[dl][cc + 8 + i];
            }
            bf16_t* dst = vt + (long)(vbase + dl) * 8192 + R0 + cc;
            *reinterpret_cast<bf16x8*>(dst)     = o0;
            *reinterpret_cast<bf16x8*>(dst + 8) = o1;
        }
    }
}

// ---------------------------------------------------------------------------
// attn: flash, block = 64 queries (4 waves M-split), seg round-robin causal
// split.  K/V double-buffered in LDS, staged T14 (loads one chunk early);
// in-loop barrier is lgkm-only so prefetches survive it.  exp2 domain.
// LDS 45KB -> 3 blocks/CU.
// ---------------------------------------------------------------------------
__global__ __launch_bounds__(256, 3) void attn_mfma(
    const bf16_t* __restrict__ qh, const bf16_t* __restrict__ kh,
    const bf16_t* __restrict__ vt,
    f16_t* __restrict__ pO, float* __restrict__ pm, float* __restrict__ pl)
{
    __shared__ __align__(16) unsigned char smem[46080];
    bf16_t (*kl)[64][72]  = reinterpret_cast<bf16_t(*)[64][72]>(smem);           // [2] 18432B
    bf16_t (*vl)[64][72]  = reinterpret_cast<bf16_t(*)[64][72]>(smem + 18432);   // [2] 18432B
    bf16_t (*P)[8][16][8] = reinterpret_cast<bf16_t(*)[8][16][8]>(smem + 36864); // [4] 8192B
    f16_t  (*ot)[16][72]  = reinterpret_cast<f16_t(*)[16][72]>(smem + 36864);    // [4] 9216B union

    const int tid = threadIdx.x, lane = tid & 63, w = tid >> 6;
    const int q4 = lane & 15, g = lane >> 4;
    const int bx = blockIdx.x, b = blockIdx.y;
    const int tile = 63 - (bx >> 3);     // heavy tiles first
    const int seg  = bx & 7;
    const int C = tile + 1;
    if (seg >= C) return;
    const long base = (long)b * TSEQ;
    const int r0 = tile * 64 + 16 * w;

    const bf16_t* qr = qh + (base + r0 + q4) * 64 + 8 * g;
    const bf16x8 qf0 = *reinterpret_cast<const bf16x8*>(qr);
    const bf16x8 qf1 = *reinterpret_cast<const bf16x8*>(qr + 32);

    // staging map: thread t: row t>>2 (0..63), cols (t&3)*16..+15
    const int srow = tid >> 2, sc = (tid & 3) * 16;
    const bf16_t* ksrc = kh + (base + srow) * 64 + sc;
    const bf16_t* vsrc = vt + (long)srow * 8192 + base + sc;
    bf16x8 kr0, kr1, vr0, vr1;
    auto loadKV = [&](int kb) {
        kr0 = *reinterpret_cast<const bf16x8*>(ksrc + (long)kb * 64);
        kr1 = *reinterpret_cast<const bf16x8*>(ksrc + (long)kb * 64 + 8);
        vr0 = *reinterpret_cast<const bf16x8*>(vsrc + kb);
        vr1 = *reinterpret_cast<const bf16x8*>(vsrc + kb + 8);
    };
    auto writeKV = [&](int buf) {
        *reinterpret_cast<bf16x8*>(&kl[buf][srow][sc])     = kr0;
        *reinterpret_cast<bf16x8*>(&kl[buf][srow][sc + 8]) = kr1;
        *reinterpret_cast<bf16x8*>(&vl[buf][srow][sc])     = vr0;
        *reinterpret_cast<bf16x8*>(&vl[buf][srow][sc + 8]) = vr1;
    };

    float m = -1e30f, l = 0.f;
    f32x4 oacc[4] = {};

    loadKV(seg << 6);
    writeKV(0);
    { int c1 = seg + SEGS; loadKV((c1 < C ? c1 : seg) << 6); }
    asm volatile("" ::: "memory");
    barrier_lds();

    int i = 0;
    for (int c = seg; c < C; c += SEGS, ++i) {
        const int buf = i & 1;
        if (c + SEGS < C) {                   // stage next chunk, issue next+1
            writeKV(buf ^ 1);
            int cn = c + 2 * SEGS;
            loadKV((cn < C ? cn : c + SEGS) << 6);
            asm volatile("" ::: "memory");    // pin prefetch issue point
        }
        const int kb = c << 6;

        // ---- QK^T (swapped): S^T rows = keys, cols = queries
        f32x4 sacc[4];
        __builtin_amdgcn_s_setprio(1);
        #pragma unroll
        for (int kt = 0; kt < 4; ++kt) {
            bf16x8 kf0 = *reinterpret_cast<const bf16x8*>(&kl[buf][kt * 16 + q4][8 * g]);
            bf16x8 kf1 = *reinterpret_cast<const bf16x8*>(&kl[buf][kt * 16 + q4][8 * g + 32]);
            f32x4 a = {};
            a = __builtin_amdgcn_mfma_f32_16x16x32_bf16(kf0, qf0, a, 0, 0, 0);
            a = __builtin_amdgcn_mfma_f32_16x16x32_bf16(kf1, qf1, a, 0, 0, 0);
            sacc[kt] = a;
        }
        __builtin_amdgcn_s_setprio(0);

        // ---- online softmax (exp2 domain; lane: 16 scores of query q4)
        float p[16];
        const bool diag = (c == C - 1);
        float mx = -1e30f;
        #pragma unroll
        for (int kt = 0; kt < 4; ++kt)
            #pragma unroll
            for (int r = 0; r < 4; ++r) {
                float sv = sacc[kt][r];
                if (diag && (kb + kt * 16 + 4 * g + r > r0 + q4)) sv = -1e30f;
                p[kt * 4 + r] = sv;
                mx = fmaxf(mx, sv);
            }
        mx = fmaxf(mx, __shfl_xor(mx, 16));
        mx = fmaxf(mx, __shfl_xor(mx, 32));
        const float mnew = fmaxf(m, mx);
        const float alpha = __builtin_exp2f(m - mnew);
        m = mnew;
        float lsum = 0.f;
        #pragma unroll
        for (int ii = 0; ii < 16; ++ii) { p[ii] = __builtin_exp2f(p[ii] - mnew); lsum += p[ii]; }
        lsum += __shfl_xor(lsum, 16);
        lsum += __shfl_xor(lsum, 32);
        l = l * alpha + lsum;
        #pragma unroll
        for (int dt = 0; dt < 4; ++dt) oacc[dt] *= alpha;

        // ---- pack P (bf16) into this wave's LDS tile
        #pragma unroll
        for (int kt = 0; kt < 4; ++kt) {
            const int cb = 2 * kt + (g >> 1);
            const int ki = (g & 1) << 2;
            bf16x4 hv = {(bf16_t)p[4*kt+0], (bf16_t)p[4*kt+1],
                         (bf16_t)p[4*kt+2], (bf16_t)p[4*kt+3]};
            *reinterpret_cast<bf16x4*>(&P[w][cb][q4][ki]) = hv;
        }
        // ---- PV: O^T += V^T x P^T
        bf16x8 ph0 = *reinterpret_cast<const bf16x8*>(&P[w][g][q4][0]);
        bf16x8 ph1 = *reinterpret_cast<const bf16x8*>(&P[w][4 + g][q4][0]);
        __builtin_amdgcn_s_setprio(1);
        #pragma unroll
        for (int dt = 0; dt < 4; ++dt) {
            bf16x8 va0 = *reinterpret_cast<const bf16x8*>(&vl[buf][dt * 16 + q4][8 * g]);
            bf16x8 va1 = *reinterpret_cast<const bf16x8*>(&vl[buf][dt * 16 + q4][8 * g + 32]);
            oacc[dt] = __builtin_amdgcn_mfma_f32_16x16x32_bf16(va0, ph0, oacc[dt], 0, 0, 0);
            oacc[dt] = __builtin_amdgcn_mfma_f32_16x16x32_bf16(va1, ph1, oacc[dt], 0, 0, 0);
        }
        __builtin_amdgcn_s_setprio(0);
        barrier_lds();   // lgkm-only: global prefetch stays in flight
    }

    // ---- epilogue: normalize, transpose via per-wave LDS (f16), store partial
    const float invl = 1.0f / l;
    #pragma unroll
    for (int dt = 0; dt < 4; ++dt)
        #pragma unroll
        for (int r = 0; r < 4; ++r)
            ot[w][q4][dt * 16 + 4 * g + r] = (f16_t)(oacc[dt][r] * invl);

    const long pbase = (((long)b * 64 + tile) * SEGS + seg) * 64;
    {
        const int q  = lane >> 2;
        const int dc = (lane & 3) * 16;
        f16x8 o0 = *reinterpret_cast<const f16x8*>(&ot[w][q][dc]);
        f16x8 o1 = *reinterpret_cast<const f16x8*>(&ot[w][q][dc + 8]);
        f16_t* dst = pO + (pbase + 16 * w + q) * 64 + dc;
        *reinterpret_cast<f16x8*>(dst)     = o0;
        *reinterpret_cast<f16x8*>(dst + 8) = o1;
    }
    if (g == 0) {
        pm[pbase + 16 * w + q4] = m;
        pl[pbase + 16 * w + q4] = l;
    }
}

// ---------------------------------------------------------------------------
// merge: combine active segs per 64q tile -> final O (fp32).  exp2 domain.
// ---------------------------------------------------------------------------
__global__ __launch_bounds__(256) void merge_k(
    const f16_t* __restrict__ pO, const float* __restrict__ pm,
    const float* __restrict__ pl, float* __restrict__ O)
{
    const int tile = blockIdx.x, b = blockIdx.y;
    const int C = tile + 1;
    const int S = (C < SEGS) ? C : SEGS;
    const int t = threadIdx.x;
    const int q = t >> 2, dc = (t & 3) * 16;
    const long pb = ((long)b * 64 + tile) * SEGS;

    float mstar = -1e30f;
    for (int s = 0; s < S; ++s) mstar = fmaxf(mstar, pm[(pb + s) * 64 + q]);
    float L = 0.f;
    float o[16];
    #pragma unroll
    for (int i = 0; i < 16; ++i) o[i] = 0.f;
    for (int s = 0; s < S; ++s) {
        const float ws = __builtin_exp2f(pm[(pb + s) * 64 + q] - mstar) * pl[(pb + s) * 64 + q];
        L += ws;
        const f16_t* src = pO + ((pb + s) * 64 + q) * 64 + dc;
        f16x8 a0 = *reinterpret_cast<const f16x8*>(src);
        f16x8 a1 = *reinterpret_cast<const f16x8*>(src + 8);
        #pragma unroll
        for (int i = 0; i < 8; ++i) {
            o[i]     += ws * (float)a0[i];
            o[8 + i] += ws * (float)a1[i];
        }
    }
    const float inv = 1.0f / L;
    float* dst = O + ((long)b * TSEQ + tile * 64 + q) * 64 + dc;
    #pragma unroll
    for (int i = 0; i < 4; ++i) {
        f32x4 v = {o[4*i] * inv, o[4*i+1] * inv, o[4*i+2] * inv, o[4*i+3] * inv};
        *reinterpret_cast<f32x4*>(dst + 4 * i) = v;
    }
}

extern "C" void kernel_launch(void* const* d_in, const int* in_sizes, int n_in,
                              void* d_out, int out_size, void* d_ws, size_t ws_size,
                              hipStream_t stream)
{
    const float* X  = (const float*)d_in[0];
    const float* Wq = (const float*)d_in[1];
    const float* Wk = (const float*)d_in[2];
    const float* Wv = (const float*)d_in[3];
    float* O = (float*)d_out;

    char* ws = (char*)d_ws;
    size_t off = 0;
    bf16_t* wT = (bf16_t*)(ws + off); off += 192 * 1024 * sizeof(bf16_t);
    bf16_t* qh = (bf16_t*)(ws + off); off += 8192L * 64 * sizeof(bf16_t);
    bf16_t* kh = (bf16_t*)(ws + off); off += 8192L * 64 * sizeof(bf16_t);
    bf16_t* vt = (bf16_t*)(ws + off); off += 64L * 8192 * sizeof(bf16_t);
    f16_t*  pO = (f16_t*)(ws + off);  off += 2L * 64 * SEGS * 64 * 64 * sizeof(f16_t);
    float*  pm = (float*)(ws + off);  off += 2L * 64 * SEGS * 64 * sizeof(float);
    float*  pl = (float*)(ws + off);  off += 2L * 64 * SEGS * 64 * sizeof(float);

    wsplit_k <<<48, 256, 0, stream>>>(Wq, Wk, Wv, wT);
    proj_mfma<<<512, 256, 0, stream>>>(X, wT, qh, kh, vt);
    attn_mfma<<<dim3(512, 2), 256, 0, stream>>>(qh, kh, vt, pO, pm, pl);
    merge_k  <<<dim3(64, 2), 256, 0, stream>>>(pO, pm, pl, O);
}